// Round 8
// baseline (136.672 us; speedup 1.0000x reference)
//
#include <hip/hip_runtime.h>
#include <hip/hip_bf16.h>
#include <stdint.h>

// MHA forward: B=2, L=2048, HID=1024, NH=16, HD=64. fp32 in/out, bf16 MFMA inside.
// R7: (1) XCD-chunked blockIdx swizzle on both GEMMs (A-tile sharers land on
// one XCD -> L2-resident, kills 3.4x overfetch); (2) attn restructured to one
// 64-row subtile per block (4 waves x 16 rows, ALL waves active every tile),
// grid 1024 with XCD swizzle + descending-work dispatch order.

#define L_SEQ 2048
#define HID 1024
#define NHEAD 16
#define HD 64

typedef __attribute__((ext_vector_type(8))) short bf16x8;
typedef __attribute__((ext_vector_type(8))) unsigned short u16x8;
typedef __attribute__((ext_vector_type(4))) float f32x4;

__device__ __forceinline__ unsigned short f2bf(float f) {
  unsigned int u = __builtin_bit_cast(unsigned int, f);
  u += 0x7fffu + ((u >> 16) & 1u);  // RNE; inputs are finite
  return (unsigned short)(u >> 16);
}

__device__ __forceinline__ unsigned int pk2bf(float a, float b) {
  unsigned int r;
  asm("v_cvt_pk_bf16_f32 %0, %1, %2" : "=v"(r) : "v"(a), "v"(b));
  return r;  // lo = bf16(a), hi = bf16(b)
}

__device__ __forceinline__ void gl_lds16(const void* g, void* l) {
  // LDS dest is wave-uniform base + lane*16 (m104); pass uniform base.
  __builtin_amdgcn_global_load_lds(
      (const __attribute__((address_space(1))) unsigned int*)(uintptr_t)g,
      (__attribute__((address_space(3))) unsigned int*)(uint32_t)(uintptr_t)l,
      16, 0, 0);
}

__device__ __forceinline__ f32x4 mfma16(bf16x8 a, bf16x8 b, f32x4 c) {
  return __builtin_amdgcn_mfma_f32_16x16x32_bf16(a, b, c, 0, 0, 0);
}

// ---------------- fused converts (7 arrays) + lengths ----------------
__global__ __launch_bounds__(256)
void convert_all_kernel(const float* __restrict__ q, const float* __restrict__ k,
                        const float* __restrict__ v, const float* __restrict__ wq,
                        const float* __restrict__ wk, const float* __restrict__ wv,
                        const float* __restrict__ wo, const unsigned int* __restrict__ km,
                        unsigned short* __restrict__ qb, unsigned short* __restrict__ kb,
                        unsigned short* __restrict__ vb, unsigned short* __restrict__ wqb,
                        unsigned short* __restrict__ wkb, unsigned short* __restrict__ wvb,
                        unsigned short* __restrict__ wob, int* __restrict__ lens) {
  __shared__ int red[256];
  const int bid = blockIdx.x;
  const int t = threadIdx.x;
  if (bid == 8192) {
    unsigned int w0 = km[0];
    bool u8mode = (w0 != 1u);  // lengths >= 1024 so first 4 bools are all true
    for (int b = 0; b < 2; ++b) {
      int cnt = 0;
      if (u8mode) {
        const unsigned char* p = (const unsigned char*)km + b * L_SEQ;
        for (int i = t; i < L_SEQ; i += 256) cnt += (p[i] != 0) ? 1 : 0;
      } else {
        const unsigned int* p = km + b * L_SEQ;
        for (int i = t; i < L_SEQ; i += 256) cnt += (p[i] != 0) ? 1 : 0;
      }
      red[t] = cnt;
      __syncthreads();
      for (int s = 128; s > 0; s >>= 1) {
        if (t < s) red[t] += red[t + s];
        __syncthreads();
      }
      if (t == 0) lens[b] = red[0];
      __syncthreads();
    }
    return;
  }
  const float* src;
  unsigned short* dst;
  int base;
  if (bid < 6144) {
    int s = bid >> 11;
    base = (bid & 2047) * 2048;
    src = s == 0 ? q : (s == 1 ? k : v);
    dst = s == 0 ? qb : (s == 1 ? kb : vb);
  } else {
    int r = bid - 6144;
    int s = r >> 9;
    base = (r & 511) * 2048;
    src = s == 0 ? wq : (s == 1 ? wk : (s == 2 ? wv : wo));
    dst = s == 0 ? wqb : (s == 1 ? wkb : (s == 2 ? wvb : wob));
  }
  int i = base + t * 8;
  float4 a = *(const float4*)(src + i);
  float4 b4 = *(const float4*)(src + i + 4);
  u16x8 o;
  o[0] = f2bf(a.x); o[1] = f2bf(a.y); o[2] = f2bf(a.z); o[3] = f2bf(a.w);
  o[4] = f2bf(b4.x); o[5] = f2bf(b4.y); o[6] = f2bf(b4.z); o[7] = f2bf(b4.w);
  *(u16x8*)(dst + i) = o;
}

// ---------------- 128x128 GEMM core, bf16 A + bf16 W, both gl_lds,
// 2-phase double-buffered, one barrier per K-step ----------------
__device__ __forceinline__ void gemm128_bf_core(const unsigned short* __restrict__ A,
                                                const unsigned short* __restrict__ W,
                                                int m0, int n0, int K,
                                                unsigned short* As, unsigned short* Bs,
                                                f32x4 acc[4][4]) {
  const int tid = threadIdx.x;
  const int w = tid >> 6, lane = tid & 63;
  const int l15 = lane & 15, l4 = lane >> 4;
  const int wr = w >> 1, wc = w & 1;
#pragma unroll
  for (int i = 0; i < 4; ++i)
#pragma unroll
    for (int j = 0; j < 4; ++j) acc[i][j] = (f32x4){0.f, 0.f, 0.f, 0.f};

  const int nk = K >> 5;
#pragma unroll
  for (int i = 0; i < 2; ++i) {
    int c = i * 256 + tid;
    int row = c >> 2, col = (c & 3) * 8;
    gl_lds16(A + (size_t)(m0 + row) * K + col, (char*)As + (i * 256 + w * 64) * 16);
    gl_lds16(W + (size_t)(n0 + row) * K + col, (char*)Bs + (i * 256 + w * 64) * 16);
  }
  __syncthreads();

  int cur = 0;
  for (int t = 0; t < nk; ++t) {
    const int k0 = t * 32;
    if (t + 1 < nk) {
#pragma unroll
      for (int i = 0; i < 2; ++i) {
        int c = i * 256 + tid;
        int row = c >> 2, col = (c & 3) * 8;
        gl_lds16(A + (size_t)(m0 + row) * K + k0 + 32 + col,
                 (char*)As + (cur ^ 1) * 8192 + (i * 256 + w * 64) * 16);
        gl_lds16(W + (size_t)(n0 + row) * K + k0 + 32 + col,
                 (char*)Bs + (cur ^ 1) * 8192 + (i * 256 + w * 64) * 16);
      }
    }
    const unsigned short* Asb = As + cur * 4096;
    const unsigned short* Bsb = Bs + cur * 4096;
    bf16x8 af[4], bfr[4];
#pragma unroll
    for (int i = 0; i < 4; ++i)
      af[i] = *(const bf16x8*)(Asb + (wr * 64 + i * 16 + l15) * 32 + l4 * 8);
#pragma unroll
    for (int j = 0; j < 4; ++j)
      bfr[j] = *(const bf16x8*)(Bsb + (wc * 64 + j * 16 + l15) * 32 + l4 * 8);
    __builtin_amdgcn_s_setprio(1);
#pragma unroll
    for (int i = 0; i < 4; ++i)
#pragma unroll
      for (int j = 0; j < 4; ++j) acc[i][j] = mfma16(af[i], bfr[j], acc[i][j]);
    __builtin_amdgcn_s_setprio(0);
    __syncthreads();  // drains gl_lds AFTER compute
    cur ^= 1;
  }
}

// ---------------- fused QKV projection (flat grid 768, XCD-chunked swizzle) ----------------
__global__ __launch_bounds__(256)
void qkv_gemm_kernel(const unsigned short* __restrict__ qb, const unsigned short* __restrict__ kb,
                     const unsigned short* __restrict__ vb, const unsigned short* __restrict__ wq,
                     const unsigned short* __restrict__ wk, const unsigned short* __restrict__ wv,
                     const float* __restrict__ bq, const float* __restrict__ bk,
                     const float* __restrict__ bv, unsigned short* __restrict__ Qp,
                     unsigned short* __restrict__ Kp, unsigned short* __restrict__ Vtp) {
  __shared__ unsigned short As[2 * 128 * 32];
  __shared__ unsigned short Bs[2 * 128 * 32];
  // XCD-chunked bijective swizzle: 768 blocks, 8 XCDs, 96 per XCD.
  // XCD c gets a contiguous slab (12 m-tiles x 8 n-tiles, ~one z) -> A+W L2-resident.
  const int id = blockIdx.x;
  const int swz = (id & 7) * 96 + (id >> 3);
  const int z = swz >> 8;
  const int rem = swz & 255;
  const int m0 = (rem >> 3) * 128, n0 = (rem & 7) * 128;

  const unsigned short* A = z == 0 ? qb : (z == 1 ? kb : vb);
  const unsigned short* W = z == 0 ? wq : (z == 1 ? wk : wv);
  const float* bias = z == 0 ? bq : (z == 1 ? bk : bv);
  f32x4 acc[4][4];
  gemm128_bf_core(A, W, m0, n0, HID, As, Bs, acc);

  const int tid = threadIdx.x;
  const int w = tid >> 6, lane = tid & 63;
  const int l15 = lane & 15, l4 = lane >> 4;
  const int wr = w >> 1, wc = w & 1;
  // Q gets 1/sqrt(64) * log2(e) folded in -> softmax runs in exp2 domain.
  const float scale = (z == 0) ? 0.125f * 1.44269504089f : 1.0f;
  if (z == 2) {
    // V^T: r=0..3 contiguous along ll -> one 8B packed store per (i,j)
#pragma unroll
    for (int i = 0; i < 4; ++i)
#pragma unroll
      for (int j = 0; j < 4; ++j) {
        int grow0 = m0 + wr * 64 + i * 16 + l4 * 4;
        int gcol = n0 + wc * 64 + j * 16 + l15;
        float bv_ = bias[gcol];
        int bb = grow0 >> 11, ll0 = grow0 & 2047;
        int hh = gcol >> 6, d = gcol & 63;
        uint2 pw;
        pw.x = pk2bf(acc[i][j][0] + bv_, acc[i][j][1] + bv_);
        pw.y = pk2bf(acc[i][j][2] + bv_, acc[i][j][3] + bv_);
        *(uint2*)(&Vtp[((size_t)(bb * NHEAD + hh) * HD + d) * L_SEQ + ll0]) = pw;
      }
  } else {
    unsigned short* P = (z == 0) ? Qp : Kp;
#pragma unroll
    for (int i = 0; i < 4; ++i)
#pragma unroll
      for (int j = 0; j < 4; ++j)
#pragma unroll
        for (int r = 0; r < 4; ++r) {
          int grow = m0 + wr * 64 + i * 16 + l4 * 4 + r;
          int gcol = n0 + wc * 64 + j * 16 + l15;
          float v = (acc[i][j][r] + bias[gcol]) * scale;
          int bb = grow >> 11, ll = grow & 2047;
          int hh = gcol >> 6, d = gcol & 63;
          P[((size_t)(bb * NHEAD + hh) * L_SEQ + ll) * HD + d] = f2bf(v);
        }
  }
}

// ---------------- output projection (flat grid 256, XCD swizzle) ----------------
__global__ __launch_bounds__(256)
void out_gemm_kernel(const unsigned short* __restrict__ att, const unsigned short* __restrict__ wo,
                     const float* __restrict__ bo, float* __restrict__ out) {
  __shared__ unsigned short As[2 * 128 * 32];
  __shared__ unsigned short Bs[2 * 128 * 32];
  const int id = blockIdx.x;
  const int swz = (id & 7) * 32 + (id >> 3);
  const int m0 = (swz >> 3) * 128, n0 = (swz & 7) * 128;
  f32x4 acc[4][4];
  gemm128_bf_core(att, wo, m0, n0, HID, As, Bs, acc);

  const int tid = threadIdx.x;
  const int w = tid >> 6, lane = tid & 63;
  const int l15 = lane & 15, l4 = lane >> 4;
  const int wr = w >> 1, wc = w & 1;
#pragma unroll
  for (int i = 0; i < 4; ++i)
#pragma unroll
    for (int j = 0; j < 4; ++j)
#pragma unroll
      for (int r = 0; r < 4; ++r) {
        int grow = m0 + wr * 64 + i * 16 + l4 * 4 + r;
        int gcol = n0 + wc * 64 + j * 16 + l15;
        out[(size_t)grow * HID + gcol] = acc[i][j][r] + bo[gcol];
      }
}

// ---------------- flash attention: one 64-row subtile per block ----------------
// grid = 1024 flat. swz = XCD-chunked(id); bh = swz>>5; sub = 31 - (swz&31)
// (descending work within each XCD chunk -> longest blocks dispatch first).
// 4 waves x 16 q-rows; ALL waves active on EVERY kv tile (k0 <= sub*64 <= qw0).
__global__ __launch_bounds__(256)
void attn_kernel(const unsigned short* __restrict__ Qp, const unsigned short* __restrict__ Kp,
                 const unsigned short* __restrict__ Vtp, unsigned short* __restrict__ att,
                 const int* __restrict__ lens) {
  __shared__ unsigned short Ks[2][64 * 64];   // [buf][k][d], XOR-swizzled 16B chunks
  __shared__ unsigned short Vs[2][64 * 64];   // [buf][d][k], XOR-swizzled 16B chunks
  __shared__ unsigned short Ps[4][16 * 72];   // wave-private P [q][k], padded stride 72

  const int id = blockIdx.x;
  const int swz = (id & 7) * 128 + (id >> 3);
  const int bh = swz >> 5;
  const int sub = 31 - (swz & 31);
  const int b = bh >> 4, h = bh & 15;
  const int tid = threadIdx.x, w = tid >> 6, lane = tid & 63;
  const int l15 = lane & 15, l4 = lane >> 4;
  const int len = lens[b];
  const int qw0 = sub * 64 + w * 16;

  const unsigned short* Qg = Qp + (size_t)bh * L_SEQ * HD;
  const unsigned short* Kg = Kp + (size_t)bh * L_SEQ * HD;
  const unsigned short* Vg = Vtp + (size_t)bh * HD * L_SEQ;

  // staging: 2 chunks of K + 2 of V per thread (chunk c: rr=c>>3, cb=c&7; src pre-swizzled)
  const int c0 = tid, c1 = tid + 256;
  const int rr0 = c0 >> 3, sz0 = ((c0 & 7) ^ (rr0 & 7)) * 8;
  const int rr1 = c1 >> 3, sz1 = ((c1 & 7) ^ (rr1 & 7)) * 8;
  const unsigned short* Kg0 = Kg + (size_t)rr0 * HD + sz0;      // + k0*HD
  const unsigned short* Kg1 = Kg + (size_t)rr1 * HD + sz1;
  const unsigned short* Vg0 = Vg + (size_t)rr0 * L_SEQ + sz0;   // + k0
  const unsigned short* Vg1 = Vg + (size_t)rr1 * L_SEQ + sz1;

  // Q fragments hoisted (B-operand: col = lane&15 = q, 8 contiguous d per lane)
  bf16x8 qf[2];
#pragma unroll
  for (int kk = 0; kk < 2; ++kk)
    qf[kk] = *(const bf16x8*)(Qg + (size_t)(qw0 + l15) * HD + kk * 32 + l4 * 8);

  f32x4 acc[4];
#pragma unroll
  for (int n = 0; n < 4; ++n) acc[n] = (f32x4){0.f, 0.f, 0.f, 0.f};
  float mq = -1e30f, lq = 0.f;  // stats for q = qw0 + l15 (replicated over l4)

  // swizzled LDS read offsets (same formula for Ks and Vs tiles)
  int koff[4][2];
#pragma unroll
  for (int n = 0; n < 4; ++n)
#pragma unroll
    for (int kk = 0; kk < 2; ++kk) {
      int row = n * 16 + l15;
      koff[n][kk] = row * 128 + (((l4 + kk * 4) ^ (row & 7)) * 16);
    }

  const int len_r = ((len + 63) >> 6) << 6;
  const int hi_end = (sub + 1) * 64;
  const int kv_end = (hi_end < len_r) ? hi_end : len_r;
  const int nt = kv_end >> 6;

  // prologue: stage tile 0 into buf 0
  gl_lds16(Kg0, (char*)&Ks[0][0] + c0 * 16);
  gl_lds16(Kg1, (char*)&Ks[0][0] + c1 * 16);
  gl_lds16(Vg0, (char*)&Vs[0][0] + c0 * 16);
  gl_lds16(Vg1, (char*)&Vs[0][0] + c1 * 16);
  __syncthreads();

  int cur = 0;
  for (int t = 0; t < nt; ++t) {
    const int k0 = t * 64;
    // issue next-tile staging FIRST; latency hides under compute below
    if (t + 1 < nt) {
      const size_t k1d = (size_t)(k0 + 64) * HD;
      const int k1 = k0 + 64;
      gl_lds16(Kg0 + k1d, (char*)&Ks[cur ^ 1][0] + c0 * 16);
      gl_lds16(Kg1 + k1d, (char*)&Ks[cur ^ 1][0] + c1 * 16);
      gl_lds16(Vg0 + k1, (char*)&Vs[cur ^ 1][0] + c0 * 16);
      gl_lds16(Vg1 + k1, (char*)&Vs[cur ^ 1][0] + c1 * 16);
    }
    {
      const char* Kb = (const char*)&Ks[cur][0];
      const char* Vb = (const char*)&Vs[cur][0];
      // S^T: A = K fragment (rows = k), B = Q fragment (cols = q)
      f32x4 s[4];
#pragma unroll
      for (int n = 0; n < 4; ++n) s[n] = (f32x4){0.f, 0.f, 0.f, 0.f};
      __builtin_amdgcn_s_setprio(1);
#pragma unroll
      for (int kk = 0; kk < 2; ++kk) {
#pragma unroll
        for (int n = 0; n < 4; ++n)
          s[n] = mfma16(*(const bf16x8*)(Kb + koff[n][kk]), qf[kk], s[n]);
      }
      __builtin_amdgcn_s_setprio(0);
      // causal + key-length mask: k = k0 + n*16 + l4*4 + r, q = qw0 + l15
      if (!(k0 + 63 <= qw0 && k0 + 64 <= len)) {
        const int qa = qw0 + l15;
#pragma unroll
        for (int n = 0; n < 4; ++n)
#pragma unroll
          for (int r = 0; r < 4; ++r) {
            int ka = k0 + n * 16 + l4 * 4 + r;
            if (ka > qa || ka >= len) s[n][r] = -1e30f;
          }
      }
      // lane-local softmax over this lane's 16 values (one q-row slice)
      float v01 = fmaxf(fmaxf(s[0][0], s[0][1]), fmaxf(s[0][2], s[0][3]));
      float v23 = fmaxf(fmaxf(s[1][0], s[1][1]), fmaxf(s[1][2], s[1][3]));
      float v45 = fmaxf(fmaxf(s[2][0], s[2][1]), fmaxf(s[2][2], s[2][3]));
      float v67 = fmaxf(fmaxf(s[3][0], s[3][1]), fmaxf(s[3][2], s[3][3]));
      float v = fmaxf(fmaxf(v01, v23), fmaxf(v45, v67));
      v = fmaxf(v, __shfl_xor(v, 16));
      v = fmaxf(v, __shfl_xor(v, 32));
      // defer-max (T13): rescale only when some row's max grew past THR=8
      if (!__all(v - mq <= 8.0f)) {
        float mnew = fmaxf(mq, v);
        float alpha = __builtin_amdgcn_exp2f(mq - mnew);
        mq = mnew;
        float ar[4];
#pragma unroll
        for (int r = 0; r < 4; ++r) ar[r] = __shfl(alpha, l4 * 4 + r, 64);
#pragma unroll
        for (int n = 0; n < 4; ++n)
#pragma unroll
          for (int r = 0; r < 4; ++r) acc[n][r] *= ar[r];
        lq *= alpha;
      }
      float rs = 0.f;
#pragma unroll
      for (int n = 0; n < 4; ++n)
#pragma unroll
        for (int r = 0; r < 4; ++r) {
          float p = __builtin_amdgcn_exp2f(s[n][r] - mq);
          s[n][r] = p;
          rs += p;
        }
      rs += __shfl_xor(rs, 16);
      rs += __shfl_xor(rs, 32);
      lq += rs;
      // P -> wave-private LDS [q][k]: 4 packed b64 writes (k contiguous in r)
#pragma unroll
      for (int n = 0; n < 4; ++n) {
        uint2 pw;
        pw.x = pk2bf(s[n][0], s[n][1]);
        pw.y = pk2bf(s[n][2], s[n][3]);
        *(uint2*)(&Ps[w][l15 * 72 + n * 16 + l4 * 4]) = pw;
      }
      // read back as A-operand (row = q = l15, 8 contiguous k at l4*8 + kk*32)
      bf16x8 pf[2];
#pragma unroll
      for (int kk = 0; kk < 2; ++kk)
        pf[kk] = *(const bf16x8*)(&Ps[w][l15 * 72 + kk * 32 + l4 * 8]);
      __builtin_amdgcn_s_setprio(1);
#pragma unroll
      for (int kk = 0; kk < 2; ++kk) {
#pragma unroll
        for (int n = 0; n < 4; ++n)
          acc[n] = mfma16(pf[kk], *(const bf16x8*)(Vb + koff[n][kk]), acc[n]);
      }
      __builtin_amdgcn_s_setprio(0);
    }
    __syncthreads();  // implicit vmcnt(0) drain lands AFTER compute
    cur ^= 1;
  }

  // epilogue: 1/l transposed to acc rows (q = qw0 + l4*4 + r)
  float invq = 1.0f / lq;  // every row has >=1 valid key -> lq > 0
  float invr[4];
#pragma unroll
  for (int r = 0; r < 4; ++r) invr[r] = __shfl(invq, l4 * 4 + r, 64);
#pragma unroll
  for (int r = 0; r < 4; ++r) {
    int qa = qw0 + l4 * 4 + r;
#pragma unroll
    for (int n = 0; n < 4; ++n)
      att[((size_t)(b * L_SEQ + qa)) * HID + h * HD + n * 16 + l15] = f2bf(acc[n][r] * invr[r]);
  }
}

extern "C" void kernel_launch(void* const* d_in, const int* in_sizes, int n_in,
                              void* d_out, int out_size, void* d_ws, size_t ws_size,
                              hipStream_t stream) {
  const float* query = (const float*)d_in[0];
  const float* key = (const float*)d_in[1];
  const float* value = (const float*)d_in[2];
  const unsigned int* key_mask = (const unsigned int*)d_in[3];
  // d_in[4] = attn_mask (static causal triu) -- computed in-kernel, unused
  const float* Wq = (const float*)d_in[5];
  const float* bq = (const float*)d_in[6];
  const float* Wk = (const float*)d_in[7];
  const float* bk = (const float*)d_in[8];
  const float* Wv = (const float*)d_in[9];
  const float* bv = (const float*)d_in[10];
  const float* Wo = (const float*)d_in[11];
  const float* bo = (const float*)d_in[12];

  char* ws = (char*)d_ws;
  const size_t SZ_X = (size_t)4096 * 1024 * 2;  // 8 MiB (bf16 activation)
  const size_t SZ_W = (size_t)1024 * 1024 * 2;  // 2 MiB (bf16 weight)
  unsigned short* qb = (unsigned short*)(ws);
  unsigned short* kb = (unsigned short*)(ws + SZ_X);
  unsigned short* vb = (unsigned short*)(ws + 2 * SZ_X);
  unsigned short* wqb = (unsigned short*)(ws + 3 * SZ_X);
  unsigned short* wkb = (unsigned short*)(ws + 3 * SZ_X + SZ_W);
  unsigned short* wvb = (unsigned short*)(ws + 3 * SZ_X + 2 * SZ_W);
  unsigned short* wob = (unsigned short*)(ws + 3 * SZ_X + 3 * SZ_W);
  unsigned short* Qp = (unsigned short*)(ws + 3 * SZ_X + 4 * SZ_W);
  unsigned short* Kp = (unsigned short*)(ws + 4 * SZ_X + 4 * SZ_W);
  unsigned short* Vtp = (unsigned short*)(ws + 5 * SZ_X + 4 * SZ_W);
  unsigned short* att = (unsigned short*)(ws + 6 * SZ_X + 4 * SZ_W);
  int* lens = (int*)(ws + 7 * SZ_X + 4 * SZ_W);

  convert_all_kernel<<<8193, 256, 0, stream>>>(query, key, value, Wq, Wk, Wv, Wo, key_mask,
                                               qb, kb, vb, wqb, wkb, wvb, wob, lens);
  qkv_gemm_kernel<<<768, 256, 0, stream>>>(qb, kb, vb, wqb, wkb, wvb, bq, bk, bv,
                                           Qp, Kp, Vtp);
  attn_kernel<<<1024, 256, 0, stream>>>(Qp, Kp, Vtp, att, lens);
  out_gemm_kernel<<<256, 256, 0, stream>>>(att, wob, bo, (float*)d_out);
}

// Round 9
// 127.036 us; speedup vs baseline: 1.0758x; 1.0758x over previous
//
#include <hip/hip_runtime.h>
#include <hip/hip_bf16.h>
#include <stdint.h>

// MHA forward: B=2, L=2048, HID=1024, NH=16, HD=64. fp32 in/out, bf16 MFMA inside.
// R9: (1) attn reverted to proven 512-thr paired-subtile form (R6/R7) + XCD-chunked
// flat grid (same-bh blocks share K/V on one XCD L2). (2) qkv fuses f32->bf16 A
// conversion in-kernel -- R5 retry with fixes: XOR-swizzled A LDS write/read
// (kills 16-way conflict) and n-fastest XCD-chunked block mapping (kills A
// overfetch). Convert pass shrinks to weights+lengths.

#define L_SEQ 2048
#define HID 1024
#define NHEAD 16
#define HD 64

typedef __attribute__((ext_vector_type(8))) short bf16x8;
typedef __attribute__((ext_vector_type(8))) unsigned short u16x8;
typedef __attribute__((ext_vector_type(4))) float f32x4;

__device__ __forceinline__ unsigned short f2bf(float f) {
  unsigned int u = __builtin_bit_cast(unsigned int, f);
  u += 0x7fffu + ((u >> 16) & 1u);  // RNE; inputs are finite
  return (unsigned short)(u >> 16);
}

__device__ __forceinline__ unsigned int pk2bf(float a, float b) {
  unsigned int r;
  asm("v_cvt_pk_bf16_f32 %0, %1, %2" : "=v"(r) : "v"(a), "v"(b));
  return r;  // lo = bf16(a), hi = bf16(b)
}

__device__ __forceinline__ void gl_lds16(const void* g, void* l) {
  __builtin_amdgcn_global_load_lds(
      (const __attribute__((address_space(1))) unsigned int*)(uintptr_t)g,
      (__attribute__((address_space(3))) unsigned int*)(uint32_t)(uintptr_t)l,
      16, 0, 0);
}

__device__ __forceinline__ f32x4 mfma16(bf16x8 a, bf16x8 b, f32x4 c) {
  return __builtin_amdgcn_mfma_f32_16x16x32_bf16(a, b, c, 0, 0, 0);
}

// ---------------- converts (weights only) + lengths ----------------
__global__ __launch_bounds__(256)
void convert_w_kernel(const float* __restrict__ wq, const float* __restrict__ wk,
                      const float* __restrict__ wv, const float* __restrict__ wo,
                      const unsigned int* __restrict__ km,
                      unsigned short* __restrict__ wqb, unsigned short* __restrict__ wkb,
                      unsigned short* __restrict__ wvb, unsigned short* __restrict__ wob,
                      int* __restrict__ lens) {
  __shared__ int red[256];
  const int bid = blockIdx.x;
  const int t = threadIdx.x;
  if (bid == 2048) {
    unsigned int w0 = km[0];
    bool u8mode = (w0 != 1u);  // lengths >= 1024 so first 4 bools are all true
    for (int b = 0; b < 2; ++b) {
      int cnt = 0;
      if (u8mode) {
        const unsigned char* p = (const unsigned char*)km + b * L_SEQ;
        for (int i = t; i < L_SEQ; i += 256) cnt += (p[i] != 0) ? 1 : 0;
      } else {
        const unsigned int* p = km + b * L_SEQ;
        for (int i = t; i < L_SEQ; i += 256) cnt += (p[i] != 0) ? 1 : 0;
      }
      red[t] = cnt;
      __syncthreads();
      for (int s = 128; s > 0; s >>= 1) {
        if (t < s) red[t] += red[t + s];
        __syncthreads();
      }
      if (t == 0) lens[b] = red[0];
      __syncthreads();
    }
    return;
  }
  int s = bid >> 9;
  int base = (bid & 511) * 2048;
  const float* src = s == 0 ? wq : (s == 1 ? wk : (s == 2 ? wv : wo));
  unsigned short* dst = s == 0 ? wqb : (s == 1 ? wkb : (s == 2 ? wvb : wob));
  int i = base + t * 8;
  float4 a = *(const float4*)(src + i);
  float4 b4 = *(const float4*)(src + i + 4);
  u16x8 o;
  o[0] = f2bf(a.x); o[1] = f2bf(a.y); o[2] = f2bf(a.z); o[3] = f2bf(a.w);
  o[4] = f2bf(b4.x); o[5] = f2bf(b4.y); o[6] = f2bf(b4.z); o[7] = f2bf(b4.w);
  *(u16x8*)(dst + i) = o;
}

// ---------------- fused QKV projection: f32 A (reg-cvt, swizzled LDS) + bf16 W ----------------
// grid 768 flat. g = (id&7)*96 + id>>3 -> XCD slab of 12 m-tiles, n fastest:
// each A m-tile (512KB f32) is hot across its 8 consecutive n-blocks.
__global__ __launch_bounds__(256)
void qkv_gemm_kernel(const float* __restrict__ qf32, const float* __restrict__ kf32,
                     const float* __restrict__ vf32, const unsigned short* __restrict__ wq,
                     const unsigned short* __restrict__ wk, const unsigned short* __restrict__ wv,
                     const float* __restrict__ bq, const float* __restrict__ bk,
                     const float* __restrict__ bv, unsigned short* __restrict__ Qp,
                     unsigned short* __restrict__ Kp, unsigned short* __restrict__ Vtp) {
  __shared__ unsigned short As[2 * 128 * 32];
  __shared__ unsigned short Bs[2 * 128 * 32];
  const int id = blockIdx.x;
  const int g = (id & 7) * 96 + (id >> 3);
  const int mg = g >> 3;                 // 0..95 global m-tile (z-major)
  const int z = mg >> 5;
  const int m0 = (mg & 31) * 128;
  const int n0 = (g & 7) * 128;

  const float* A = z == 0 ? qf32 : (z == 1 ? kf32 : vf32);
  const unsigned short* W = z == 0 ? wq : (z == 1 ? wk : wv);
  const float* bias = z == 0 ? bq : (z == 1 ? bk : bv);

  const int tid = threadIdx.x;
  const int w = tid >> 6, lane = tid & 63;
  const int l15 = lane & 15, l4 = lane >> 4;
  const int wr = w >> 1, wc = w & 1;

  f32x4 acc[4][4];
#pragma unroll
  for (int i = 0; i < 4; ++i)
#pragma unroll
    for (int j = 0; j < 4; ++j) acc[i][j] = (f32x4){0.f, 0.f, 0.f, 0.f};

  // A staging: thread t -> row t>>1, chunks ac, ac+1 (16B bf16 each = 8 f32 src)
  const int arow = tid >> 1;
  const int ac = (tid & 1) * 2;
  const float* Ag = A + (size_t)(m0 + arow) * HID + ac * 8;
  const int c0s = (ac) ^ ((arow >> 1) & 3);        // XOR chunk swizzle
  const int c1s = (ac + 1) ^ ((arow >> 1) & 3);
  char* As0 = (char*)As + arow * 64 + c0s * 16;
  char* As1 = (char*)As + arow * 64 + c1s * 16;

  // af read offsets (same swizzle)
  int aoff[4];
#pragma unroll
  for (int i = 0; i < 4; ++i) {
    int R = wr * 64 + i * 16 + l15;
    aoff[i] = R * 64 + ((l4 ^ ((R >> 1) & 3)) * 16);
  }

  // prologue: tile 0 -> buf 0
  {
    float4 a0 = *(const float4*)(Ag);
    float4 a1 = *(const float4*)(Ag + 4);
    float4 a2 = *(const float4*)(Ag + 8);
    float4 a3 = *(const float4*)(Ag + 12);
    uint4 p0, p1;
    p0.x = pk2bf(a0.x, a0.y); p0.y = pk2bf(a0.z, a0.w);
    p0.z = pk2bf(a1.x, a1.y); p0.w = pk2bf(a1.z, a1.w);
    p1.x = pk2bf(a2.x, a2.y); p1.y = pk2bf(a2.z, a2.w);
    p1.z = pk2bf(a3.x, a3.y); p1.w = pk2bf(a3.z, a3.w);
    *(uint4*)(As0) = p0;
    *(uint4*)(As1) = p1;
#pragma unroll
    for (int i = 0; i < 2; ++i) {
      int c = i * 256 + tid;
      int row = c >> 2, col = (c & 3) * 8;
      gl_lds16(W + (size_t)(n0 + row) * HID + col, (char*)Bs + (i * 256 + w * 64) * 16);
    }
  }
  __syncthreads();

  int cur = 0;
  const int nk = HID >> 5;
  for (int t = 0; t < nk; ++t) {
    const int k0 = t * 32;
    float4 a0, a1, a2, a3;
    const bool more = (t + 1 < nk);
    if (more) {
      const float* Agn = Ag + k0 + 32;
      a0 = *(const float4*)(Agn);
      a1 = *(const float4*)(Agn + 4);
      a2 = *(const float4*)(Agn + 8);
      a3 = *(const float4*)(Agn + 12);
#pragma unroll
      for (int i = 0; i < 2; ++i) {
        int c = i * 256 + tid;
        int row = c >> 2, col = (c & 3) * 8;
        gl_lds16(W + (size_t)(n0 + row) * HID + k0 + 32 + col,
                 (char*)Bs + (cur ^ 1) * 8192 + (i * 256 + w * 64) * 16);
      }
    }
    const char* Asb = (const char*)As + cur * 8192;
    const unsigned short* Bsb = Bs + cur * 4096;
    bf16x8 af[4], bfr[4];
#pragma unroll
    for (int i = 0; i < 4; ++i) af[i] = *(const bf16x8*)(Asb + aoff[i]);
#pragma unroll
    for (int j = 0; j < 4; ++j)
      bfr[j] = *(const bf16x8*)(Bsb + (wc * 64 + j * 16 + l15) * 32 + l4 * 8);
    __builtin_amdgcn_s_setprio(1);
#pragma unroll
    for (int i = 0; i < 4; ++i)
#pragma unroll
      for (int j = 0; j < 4; ++j) acc[i][j] = mfma16(af[i], bfr[j], acc[i][j]);
    __builtin_amdgcn_s_setprio(0);
    if (more) {  // cvt + write next A tile (f32 load wait lands here, after MFMA)
      uint4 p0, p1;
      p0.x = pk2bf(a0.x, a0.y); p0.y = pk2bf(a0.z, a0.w);
      p0.z = pk2bf(a1.x, a1.y); p0.w = pk2bf(a1.z, a1.w);
      p1.x = pk2bf(a2.x, a2.y); p1.y = pk2bf(a2.z, a2.w);
      p1.z = pk2bf(a3.x, a3.y); p1.w = pk2bf(a3.z, a3.w);
      *(uint4*)(As0 + (cur ^ 1) * 8192) = p0;
      *(uint4*)(As1 + (cur ^ 1) * 8192) = p1;
    }
    __syncthreads();
    cur ^= 1;
  }

  // epilogue
  const float scale = (z == 0) ? 0.125f * 1.44269504089f : 1.0f;
  if (z == 2) {
#pragma unroll
    for (int i = 0; i < 4; ++i)
#pragma unroll
      for (int j = 0; j < 4; ++j) {
        int grow0 = m0 + wr * 64 + i * 16 + l4 * 4;
        int gcol = n0 + wc * 64 + j * 16 + l15;
        float bv_ = bias[gcol];
        int bb = grow0 >> 11, ll0 = grow0 & 2047;
        int hh = gcol >> 6, d = gcol & 63;
        uint2 pw;
        pw.x = pk2bf(acc[i][j][0] + bv_, acc[i][j][1] + bv_);
        pw.y = pk2bf(acc[i][j][2] + bv_, acc[i][j][3] + bv_);
        *(uint2*)(&Vtp[((size_t)(bb * NHEAD + hh) * HD + d) * L_SEQ + ll0]) = pw;
      }
  } else {
    unsigned short* P = (z == 0) ? Qp : Kp;
#pragma unroll
    for (int i = 0; i < 4; ++i)
#pragma unroll
      for (int j = 0; j < 4; ++j)
#pragma unroll
        for (int r = 0; r < 4; ++r) {
          int grow = m0 + wr * 64 + i * 16 + l4 * 4 + r;
          int gcol = n0 + wc * 64 + j * 16 + l15;
          float v = (acc[i][j][r] + bias[gcol]) * scale;
          int bb = grow >> 11, ll = grow & 2047;
          int hh = gcol >> 6, d = gcol & 63;
          P[((size_t)(bb * NHEAD + hh) * L_SEQ + ll) * HD + d] = f2bf(v);
        }
  }
}

// ---------------- 128x128 GEMM core, bf16 A + bf16 W (out projection) ----------------
__device__ __forceinline__ void gemm128_bf_core(const unsigned short* __restrict__ A,
                                                const unsigned short* __restrict__ W,
                                                int m0, int n0, int K,
                                                unsigned short* As, unsigned short* Bs,
                                                f32x4 acc[4][4]) {
  const int tid = threadIdx.x;
  const int w = tid >> 6, lane = tid & 63;
  const int l15 = lane & 15, l4 = lane >> 4;
  const int wr = w >> 1, wc = w & 1;
#pragma unroll
  for (int i = 0; i < 4; ++i)
#pragma unroll
    for (int j = 0; j < 4; ++j) acc[i][j] = (f32x4){0.f, 0.f, 0.f, 0.f};

  const int nk = K >> 5;
#pragma unroll
  for (int i = 0; i < 2; ++i) {
    int c = i * 256 + tid;
    int row = c >> 2, col = (c & 3) * 8;
    gl_lds16(A + (size_t)(m0 + row) * K + col, (char*)As + (i * 256 + w * 64) * 16);
    gl_lds16(W + (size_t)(n0 + row) * K + col, (char*)Bs + (i * 256 + w * 64) * 16);
  }
  __syncthreads();

  int cur = 0;
  for (int t = 0; t < nk; ++t) {
    const int k0 = t * 32;
    if (t + 1 < nk) {
#pragma unroll
      for (int i = 0; i < 2; ++i) {
        int c = i * 256 + tid;
        int row = c >> 2, col = (c & 3) * 8;
        gl_lds16(A + (size_t)(m0 + row) * K + k0 + 32 + col,
                 (char*)As + (cur ^ 1) * 8192 + (i * 256 + w * 64) * 16);
        gl_lds16(W + (size_t)(n0 + row) * K + k0 + 32 + col,
                 (char*)Bs + (cur ^ 1) * 8192 + (i * 256 + w * 64) * 16);
      }
    }
    const unsigned short* Asb = As + cur * 4096;
    const unsigned short* Bsb = Bs + cur * 4096;
    bf16x8 af[4], bfr[4];
#pragma unroll
    for (int i = 0; i < 4; ++i)
      af[i] = *(const bf16x8*)(Asb + (wr * 64 + i * 16 + l15) * 32 + l4 * 8);
#pragma unroll
    for (int j = 0; j < 4; ++j)
      bfr[j] = *(const bf16x8*)(Bsb + (wc * 64 + j * 16 + l15) * 32 + l4 * 8);
    __builtin_amdgcn_s_setprio(1);
#pragma unroll
    for (int i = 0; i < 4; ++i)
#pragma unroll
      for (int j = 0; j < 4; ++j) acc[i][j] = mfma16(af[i], bfr[j], acc[i][j]);
    __builtin_amdgcn_s_setprio(0);
    __syncthreads();
    cur ^= 1;
  }
}

// ---------------- output projection (flat grid 256, XCD swizzle) ----------------
__global__ __launch_bounds__(256)
void out_gemm_kernel(const unsigned short* __restrict__ att, const unsigned short* __restrict__ wo,
                     const float* __restrict__ bo, float* __restrict__ out) {
  __shared__ unsigned short As[2 * 128 * 32];
  __shared__ unsigned short Bs[2 * 128 * 32];
  const int id = blockIdx.x;
  const int swz = (id & 7) * 32 + (id >> 3);
  const int m0 = (swz >> 3) * 128, n0 = (swz & 7) * 128;
  f32x4 acc[4][4];
  gemm128_bf_core(att, wo, m0, n0, HID, As, Bs, acc);

  const int tid = threadIdx.x;
  const int w = tid >> 6, lane = tid & 63;
  const int l15 = lane & 15, l4 = lane >> 4;
  const int wr = w >> 1, wc = w & 1;
#pragma unroll
  for (int i = 0; i < 4; ++i)
#pragma unroll
    for (int j = 0; j < 4; ++j)
#pragma unroll
      for (int r = 0; r < 4; ++r) {
        int grow = m0 + wr * 64 + i * 16 + l4 * 4 + r;
        int gcol = n0 + wc * 64 + j * 16 + l15;
        out[(size_t)grow * HID + gcol] = acc[i][j][r] + bo[gcol];
      }
}

// ---------------- flash attention (512 thr, paired subtiles, swapped softmax) ----------------
// flat grid 512; g = (id&7)*64 + id>>3: bh = g>>4 (same-bh blocks on one XCD), x = g&15.
// Block x owns subtiles {x, 31-x}: waves 0-3 -> subtile x, waves 4-7 -> 31-x.
__global__ __launch_bounds__(512)
void attn_kernel(const unsigned short* __restrict__ Qp, const unsigned short* __restrict__ Kp,
                 const unsigned short* __restrict__ Vtp, unsigned short* __restrict__ att,
                 const int* __restrict__ lens) {
  __shared__ unsigned short Ks[2][64 * 64];   // [buf][k][d], XOR-swizzled 16B chunks
  __shared__ unsigned short Vs[2][64 * 64];   // [buf][d][k], XOR-swizzled 16B chunks
  __shared__ unsigned short Ps[8][16 * 72];   // wave-private P [q][k], padded stride 72

  const int id = blockIdx.x;
  const int g = (id & 7) * 64 + (id >> 3);
  const int bh = g >> 4;
  const int x = g & 15;
  const int b = bh >> 4, h = bh & 15;
  const int tid = threadIdx.x, w = tid >> 6, lane = tid & 63;
  const int l15 = lane & 15, l4 = lane >> 4;
  const int len = lens[b];
  const int sub = (w < 4) ? x : (31 - x);
  const int qw0 = sub * 64 + (w & 3) * 16;

  const unsigned short* Qg = Qp + (size_t)bh * L_SEQ * HD;
  const unsigned short* Kg = Kp + (size_t)bh * L_SEQ * HD;
  const unsigned short* Vg = Vtp + (size_t)bh * HD * L_SEQ;

  // staging addresses: thread -> (row rr, 16B chunk cb), source pre-swizzled
  const int rr = tid >> 3, cb = tid & 7;
  const int swz = (cb ^ (rr & 7)) * 8;
  const unsigned short* KgRow = Kg + (size_t)rr * HD + swz;       // + k0*HD
  const unsigned short* VgRow = Vg + (size_t)rr * L_SEQ + swz;    // + k0

  // Q fragments hoisted (B-operand: col = lane&15 = q, 8 contiguous d per lane)
  bf16x8 qf[2];
#pragma unroll
  for (int kk = 0; kk < 2; ++kk)
    qf[kk] = *(const bf16x8*)(Qg + (size_t)(qw0 + l15) * HD + kk * 32 + l4 * 8);

  f32x4 acc[4];
#pragma unroll
  for (int n = 0; n < 4; ++n) acc[n] = (f32x4){0.f, 0.f, 0.f, 0.f};
  float mq = -1e30f, lq = 0.f;  // stats for q = qw0 + l15 (replicated over l4)

  int koff[4][2];
#pragma unroll
  for (int n = 0; n < 4; ++n)
#pragma unroll
    for (int kk = 0; kk < 2; ++kk) {
      int row = n * 16 + l15;
      koff[n][kk] = row * 128 + (((l4 + kk * 4) ^ (row & 7)) * 16);
    }

  const int len_r = ((len + 63) >> 6) << 6;
  const int hi_end = 64 * (32 - x);
  const int kv_end = (hi_end < len_r) ? hi_end : len_r;
  const int nt = kv_end >> 6;

  gl_lds16(KgRow, (char*)&Ks[0][0] + w * 1024);
  gl_lds16(VgRow, (char*)&Vs[0][0] + w * 1024);
  __syncthreads();

  int cur = 0;
  for (int t = 0; t < nt; ++t) {
    const int k0 = t * 64;
    if (t + 1 < nt) {
      const int k1 = k0 + 64;
      gl_lds16(KgRow + (size_t)k1 * HD, (char*)&Ks[cur ^ 1][0] + w * 1024);
      gl_lds16(VgRow + k1, (char*)&Vs[cur ^ 1][0] + w * 1024);
    }
    if (k0 <= qw0 + 15) {
      const char* Kb = (const char*)&Ks[cur][0];
      const char* Vb = (const char*)&Vs[cur][0];
      f32x4 s[4];
#pragma unroll
      for (int n = 0; n < 4; ++n) s[n] = (f32x4){0.f, 0.f, 0.f, 0.f};
      __builtin_amdgcn_s_setprio(1);
#pragma unroll
      for (int kk = 0; kk < 2; ++kk) {
#pragma unroll
        for (int n = 0; n < 4; ++n)
          s[n] = mfma16(*(const bf16x8*)(Kb + koff[n][kk]), qf[kk], s[n]);
      }
      __builtin_amdgcn_s_setprio(0);
      if (!(k0 + 63 <= qw0 && k0 + 64 <= len)) {
        const int qa = qw0 + l15;
#pragma unroll
        for (int n = 0; n < 4; ++n)
#pragma unroll
          for (int r = 0; r < 4; ++r) {
            int ka = k0 + n * 16 + l4 * 4 + r;
            if (ka > qa || ka >= len) s[n][r] = -1e30f;
          }
      }
      float v01 = fmaxf(fmaxf(s[0][0], s[0][1]), fmaxf(s[0][2], s[0][3]));
      float v23 = fmaxf(fmaxf(s[1][0], s[1][1]), fmaxf(s[1][2], s[1][3]));
      float v45 = fmaxf(fmaxf(s[2][0], s[2][1]), fmaxf(s[2][2], s[2][3]));
      float v67 = fmaxf(fmaxf(s[3][0], s[3][1]), fmaxf(s[3][2], s[3][3]));
      float v = fmaxf(fmaxf(v01, v23), fmaxf(v45, v67));
      v = fmaxf(v, __shfl_xor(v, 16));
      v = fmaxf(v, __shfl_xor(v, 32));
      if (!__all(v - mq <= 8.0f)) {  // defer-max (T13), exp2 domain
        float mnew = fmaxf(mq, v);
        float alpha = __builtin_amdgcn_exp2f(mq - mnew);
        mq = mnew;
        float ar[4];
#pragma unroll
        for (int r = 0; r < 4; ++r) ar[r] = __shfl(alpha, l4 * 4 + r, 64);
#pragma unroll
        for (int n = 0; n < 4; ++n)
#pragma unroll
          for (int r = 0; r < 4; ++r) acc[n][r] *= ar[r];
        lq *= alpha;
      }
      float rs = 0.f;
#pragma unroll
      for (int n = 0; n < 4; ++n)
#pragma unroll
        for (int r = 0; r < 4; ++r) {
          float p = __builtin_amdgcn_exp2f(s[n][r] - mq);
          s[n][r] = p;
          rs += p;
        }
      rs += __shfl_xor(rs, 16);
      rs += __shfl_xor(rs, 32);
      lq += rs;
#pragma unroll
      for (int n = 0; n < 4; ++n) {
        uint2 pw;
        pw.x = pk2bf(s[n][0], s[n][1]);
        pw.y = pk2bf(s[n][2], s[n][3]);
        *(uint2*)(&Ps[w][l15 * 72 + n * 16 + l4 * 4]) = pw;
      }
      bf16x8 pf[2];
#pragma unroll
      for (int kk = 0; kk < 2; ++kk)
        pf[kk] = *(const bf16x8*)(&Ps[w][l15 * 72 + kk * 32 + l4 * 8]);
      __builtin_amdgcn_s_setprio(1);
#pragma unroll
      for (int kk = 0; kk < 2; ++kk) {
#pragma unroll
        for (int n = 0; n < 4; ++n)
          acc[n] = mfma16(pf[kk], *(const bf16x8*)(Vb + koff[n][kk]), acc[n]);
      }
      __builtin_amdgcn_s_setprio(0);
    }
    __syncthreads();
    cur ^= 1;
  }

  float invq = 1.0f / lq;
  float invr[4];
#pragma unroll
  for (int r = 0; r < 4; ++r) invr[r] = __shfl(invq, l4 * 4 + r, 64);
#pragma unroll
  for (int r = 0; r < 4; ++r) {
    int qa = qw0 + l4 * 4 + r;
#pragma unroll
    for (int n = 0; n < 4; ++n)
      att[((size_t)(b * L_SEQ + qa)) * HID + h * HD + n * 16 + l15] = f2bf(acc[n][r] * invr[r]);
  }
}

extern "C" void kernel_launch(void* const* d_in, const int* in_sizes, int n_in,
                              void* d_out, int out_size, void* d_ws, size_t ws_size,
                              hipStream_t stream) {
  const float* query = (const float*)d_in[0];
  const float* key = (const float*)d_in[1];
  const float* value = (const float*)d_in[2];
  const unsigned int* key_mask = (const unsigned int*)d_in[3];
  // d_in[4] = attn_mask (static causal triu) -- computed in-kernel, unused
  const float* Wq = (const float*)d_in[5];
  const float* bq = (const float*)d_in[6];
  const float* Wk = (const float*)d_in[7];
  const float* bk = (const float*)d_in[8];
  const float* Wv = (const float*)d_in[9];
  const float* bv = (const float*)d_in[10];
  const float* Wo = (const float*)d_in[11];
  const float* bo = (const float*)d_in[12];

  char* ws = (char*)d_ws;
  const size_t SZ_X = (size_t)4096 * 1024 * 2;  // 8 MiB
  const size_t SZ_W = (size_t)1024 * 1024 * 2;  // 2 MiB
  unsigned short* wqb = (unsigned short*)(ws + 3 * SZ_X);
  unsigned short* wkb = (unsigned short*)(ws + 3 * SZ_X + SZ_W);
  unsigned short* wvb = (unsigned short*)(ws + 3 * SZ_X + 2 * SZ_W);
  unsigned short* wob = (unsigned short*)(ws + 3 * SZ_X + 3 * SZ_W);
  unsigned short* Qp = (unsigned short*)(ws + 3 * SZ_X + 4 * SZ_W);
  unsigned short* Kp = (unsigned short*)(ws + 4 * SZ_X + 4 * SZ_W);
  unsigned short* Vtp = (unsigned short*)(ws + 5 * SZ_X + 4 * SZ_W);
  unsigned short* att = (unsigned short*)(ws + 6 * SZ_X + 4 * SZ_W);
  int* lens = (int*)(ws + 7 * SZ_X + 4 * SZ_W);

  convert_w_kernel<<<2049, 256, 0, stream>>>(Wq, Wk, Wv, Wo, key_mask,
                                             wqb, wkb, wvb, wob, lens);
  qkv_gemm_kernel<<<768, 256, 0, stream>>>(query, key, value, wqb, wkb, wvb,
                                           bq, bk, bv, Qp, Kp, Vtp);
  attn_kernel<<<512, 512, 0, stream>>>(Qp, Kp, Vtp, att, lens);
  out_gemm_kernel<<<256, 256, 0, stream>>>(att, wob, bo, (float*)d_out);
}

// Round 10
// 123.223 us; speedup vs baseline: 1.1091x; 1.0309x over previous
//
#include <hip/hip_runtime.h>
#include <hip/hip_bf16.h>
#include <stdint.h>

// MHA forward: B=2, L=2048, HID=1024, NH=16, HD=64. fp32 in/out, bf16 MFMA inside.
// R10: qkv stages A as RAW F32 via global_load_lds (full-iteration lookahead,
// the proven async path) and converts f32->bf16 at fragment-read time
// (swizzled ds_read_b128 + v_cvt_pk_bf16_f32). A-tile swizzle: pre-swizzled
// global source + XOR'd read (rule 21), kills the 128B-row 16-way conflict.
// attn (512-thr paired + XCD swizzle), out_gemm, convert_w unchanged from R9.

#define L_SEQ 2048
#define HID 1024
#define NHEAD 16
#define HD 64

typedef __attribute__((ext_vector_type(8))) short bf16x8;
typedef __attribute__((ext_vector_type(8))) unsigned short u16x8;
typedef __attribute__((ext_vector_type(4))) float f32x4;

__device__ __forceinline__ unsigned short f2bf(float f) {
  unsigned int u = __builtin_bit_cast(unsigned int, f);
  u += 0x7fffu + ((u >> 16) & 1u);  // RNE; inputs are finite
  return (unsigned short)(u >> 16);
}

__device__ __forceinline__ unsigned int pk2bf(float a, float b) {
  unsigned int r;
  asm("v_cvt_pk_bf16_f32 %0, %1, %2" : "=v"(r) : "v"(a), "v"(b));
  return r;  // lo = bf16(a), hi = bf16(b)
}

__device__ __forceinline__ void gl_lds16(const void* g, void* l) {
  __builtin_amdgcn_global_load_lds(
      (const __attribute__((address_space(1))) unsigned int*)(uintptr_t)g,
      (__attribute__((address_space(3))) unsigned int*)(uint32_t)(uintptr_t)l,
      16, 0, 0);
}

__device__ __forceinline__ f32x4 mfma16(bf16x8 a, bf16x8 b, f32x4 c) {
  return __builtin_amdgcn_mfma_f32_16x16x32_bf16(a, b, c, 0, 0, 0);
}

// ---------------- converts (weights only) + lengths ----------------
__global__ __launch_bounds__(256)
void convert_w_kernel(const float* __restrict__ wq, const float* __restrict__ wk,
                      const float* __restrict__ wv, const float* __restrict__ wo,
                      const unsigned int* __restrict__ km,
                      unsigned short* __restrict__ wqb, unsigned short* __restrict__ wkb,
                      unsigned short* __restrict__ wvb, unsigned short* __restrict__ wob,
                      int* __restrict__ lens) {
  __shared__ int red[256];
  const int bid = blockIdx.x;
  const int t = threadIdx.x;
  if (bid == 2048) {
    unsigned int w0 = km[0];
    bool u8mode = (w0 != 1u);  // lengths >= 1024 so first 4 bools are all true
    for (int b = 0; b < 2; ++b) {
      int cnt = 0;
      if (u8mode) {
        const unsigned char* p = (const unsigned char*)km + b * L_SEQ;
        for (int i = t; i < L_SEQ; i += 256) cnt += (p[i] != 0) ? 1 : 0;
      } else {
        const unsigned int* p = km + b * L_SEQ;
        for (int i = t; i < L_SEQ; i += 256) cnt += (p[i] != 0) ? 1 : 0;
      }
      red[t] = cnt;
      __syncthreads();
      for (int s = 128; s > 0; s >>= 1) {
        if (t < s) red[t] += red[t + s];
        __syncthreads();
      }
      if (t == 0) lens[b] = red[0];
      __syncthreads();
    }
    return;
  }
  int s = bid >> 9;
  int base = (bid & 511) * 2048;
  const float* src = s == 0 ? wq : (s == 1 ? wk : (s == 2 ? wv : wo));
  unsigned short* dst = s == 0 ? wqb : (s == 1 ? wkb : (s == 2 ? wvb : wob));
  int i = base + t * 8;
  float4 a = *(const float4*)(src + i);
  float4 b4 = *(const float4*)(src + i + 4);
  u16x8 o;
  o[0] = f2bf(a.x); o[1] = f2bf(a.y); o[2] = f2bf(a.z); o[3] = f2bf(a.w);
  o[4] = f2bf(b4.x); o[5] = f2bf(b4.y); o[6] = f2bf(b4.z); o[7] = f2bf(b4.w);
  *(u16x8*)(dst + i) = o;
}

// ---------------- fused QKV projection: f32 A via gl_lds (swizzled) + bf16 W ----------------
// grid 768 flat. g = (id&7)*96 + id>>3 -> XCD slab of 12 m-tiles, n fastest:
// each A m-tile is hot in its XCD's L2 across the 8 consecutive n-blocks.
__global__ __launch_bounds__(256)
void qkv_gemm_kernel(const float* __restrict__ qf32, const float* __restrict__ kf32,
                     const float* __restrict__ vf32, const unsigned short* __restrict__ wq,
                     const unsigned short* __restrict__ wk, const unsigned short* __restrict__ wv,
                     const float* __restrict__ bq, const float* __restrict__ bk,
                     const float* __restrict__ bv, unsigned short* __restrict__ Qp,
                     unsigned short* __restrict__ Kp, unsigned short* __restrict__ Vtp) {
  __shared__ float Asf[2 * 128 * 32];         // 32 KB: A tile in f32, dbuf
  __shared__ unsigned short Bs[2 * 128 * 32]; // 16 KB: W tile in bf16, dbuf
  const int id = blockIdx.x;
  const int g = (id & 7) * 96 + (id >> 3);
  const int mg = g >> 3;                 // 0..95 global m-tile (z-major)
  const int z = mg >> 5;
  const int m0 = (mg & 31) * 128;
  const int n0 = (g & 7) * 128;

  const float* A = z == 0 ? qf32 : (z == 1 ? kf32 : vf32);
  const unsigned short* W = z == 0 ? wq : (z == 1 ? wk : wv);
  const float* bias = z == 0 ? bq : (z == 1 ? bk : bv);

  const int tid = threadIdx.x;
  const int w = tid >> 6, lane = tid & 63;
  const int l15 = lane & 15, l4 = lane >> 4;
  const int wr = w >> 1, wc = w & 1;

  f32x4 acc[4][4];
#pragma unroll
  for (int i = 0; i < 4; ++i)
#pragma unroll
    for (int j = 0; j < 4; ++j) acc[i][j] = (f32x4){0.f, 0.f, 0.f, 0.f};

  // A staging: 1024 16B-chunks (4/thread). chunk c: row=c>>3, pos cb=c&7 holds
  // global k-chunk (cb ^ (row&7)) -> involution; LDS dest stays linear.
  // W staging: 512 chunks (2/thread), linear (proven core layout).

  // prologue: tile 0 -> buf 0
#pragma unroll
  for (int i = 0; i < 4; ++i) {
    int c = i * 256 + tid;
    int row = c >> 3, cb = c & 7;
    gl_lds16(A + (size_t)(m0 + row) * HID + ((cb ^ (row & 7)) * 4),
             (char*)Asf + c * 16);
  }
#pragma unroll
  for (int i = 0; i < 2; ++i) {
    int c = i * 256 + tid;
    int row = c >> 2, col = (c & 3) * 8;
    gl_lds16(W + (size_t)(n0 + row) * HID + col, (char*)Bs + c * 16);
  }
  __syncthreads();

  int cur = 0;
  const int nk = HID >> 5;
  for (int t = 0; t < nk; ++t) {
    const int k0 = t * 32;
    if (t + 1 < nk) {
#pragma unroll
      for (int i = 0; i < 4; ++i) {
        int c = i * 256 + tid;
        int row = c >> 3, cb = c & 7;
        gl_lds16(A + (size_t)(m0 + row) * HID + k0 + 32 + ((cb ^ (row & 7)) * 4),
                 (char*)Asf + (cur ^ 1) * 16384 + c * 16);
      }
#pragma unroll
      for (int i = 0; i < 2; ++i) {
        int c = i * 256 + tid;
        int row = c >> 2, col = (c & 3) * 8;
        gl_lds16(W + (size_t)(n0 + row) * HID + k0 + 32 + col,
                 (char*)Bs + (cur ^ 1) * 8192 + c * 16);
      }
    }
    const char* Asb = (const char*)Asf + cur * 16384;
    const unsigned short* Bsb = Bs + cur * 4096;
    bf16x8 af[4], bfr[4];
#pragma unroll
    for (int i = 0; i < 4; ++i) {
      int R = wr * 64 + i * 16 + l15;
      int s = R & 7;
      f32x4 lo = *(const f32x4*)(Asb + R * 128 + (((l4 * 2) ^ s) * 16));
      f32x4 hi = *(const f32x4*)(Asb + R * 128 + (((l4 * 2 + 1) ^ s) * 16));
      uint4 uu;
      uu.x = pk2bf(lo[0], lo[1]);
      uu.y = pk2bf(lo[2], lo[3]);
      uu.z = pk2bf(hi[0], hi[1]);
      uu.w = pk2bf(hi[2], hi[3]);
      af[i] = __builtin_bit_cast(bf16x8, uu);
    }
#pragma unroll
    for (int j = 0; j < 4; ++j)
      bfr[j] = *(const bf16x8*)(Bsb + (wc * 64 + j * 16 + l15) * 32 + l4 * 8);
    __builtin_amdgcn_s_setprio(1);
#pragma unroll
    for (int i = 0; i < 4; ++i)
#pragma unroll
      for (int j = 0; j < 4; ++j) acc[i][j] = mfma16(af[i], bfr[j], acc[i][j]);
    __builtin_amdgcn_s_setprio(0);
    __syncthreads();  // drains gl_lds AFTER compute
    cur ^= 1;
  }

  // epilogue
  const float scale = (z == 0) ? 0.125f * 1.44269504089f : 1.0f;
  if (z == 2) {
#pragma unroll
    for (int i = 0; i < 4; ++i)
#pragma unroll
      for (int j = 0; j < 4; ++j) {
        int grow0 = m0 + wr * 64 + i * 16 + l4 * 4;
        int gcol = n0 + wc * 64 + j * 16 + l15;
        float bv_ = bias[gcol];
        int bb = grow0 >> 11, ll0 = grow0 & 2047;
        int hh = gcol >> 6, d = gcol & 63;
        uint2 pw;
        pw.x = pk2bf(acc[i][j][0] + bv_, acc[i][j][1] + bv_);
        pw.y = pk2bf(acc[i][j][2] + bv_, acc[i][j][3] + bv_);
        *(uint2*)(&Vtp[((size_t)(bb * NHEAD + hh) * HD + d) * L_SEQ + ll0]) = pw;
      }
  } else {
    unsigned short* P = (z == 0) ? Qp : Kp;
#pragma unroll
    for (int i = 0; i < 4; ++i)
#pragma unroll
      for (int j = 0; j < 4; ++j)
#pragma unroll
        for (int r = 0; r < 4; ++r) {
          int grow = m0 + wr * 64 + i * 16 + l4 * 4 + r;
          int gcol = n0 + wc * 64 + j * 16 + l15;
          float v = (acc[i][j][r] + bias[gcol]) * scale;
          int bb = grow >> 11, ll = grow & 2047;
          int hh = gcol >> 6, d = gcol & 63;
          P[((size_t)(bb * NHEAD + hh) * L_SEQ + ll) * HD + d] = f2bf(v);
        }
  }
}

// ---------------- 128x128 GEMM core, bf16 A + bf16 W (out projection) ----------------
__device__ __forceinline__ void gemm128_bf_core(const unsigned short* __restrict__ A,
                                                const unsigned short* __restrict__ W,
                                                int m0, int n0, int K,
                                                unsigned short* As, unsigned short* Bs,
                                                f32x4 acc[4][4]) {
  const int tid = threadIdx.x;
  const int w = tid >> 6, lane = tid & 63;
  const int l15 = lane & 15, l4 = lane >> 4;
  const int wr = w >> 1, wc = w & 1;
#pragma unroll
  for (int i = 0; i < 4; ++i)
#pragma unroll
    for (int j = 0; j < 4; ++j) acc[i][j] = (f32x4){0.f, 0.f, 0.f, 0.f};

  const int nk = K >> 5;
#pragma unroll
  for (int i = 0; i < 2; ++i) {
    int c = i * 256 + tid;
    int row = c >> 2, col = (c & 3) * 8;
    gl_lds16(A + (size_t)(m0 + row) * K + col, (char*)As + (i * 256 + w * 64) * 16);
    gl_lds16(W + (size_t)(n0 + row) * K + col, (char*)Bs + (i * 256 + w * 64) * 16);
  }
  __syncthreads();

  int cur = 0;
  for (int t = 0; t < nk; ++t) {
    const int k0 = t * 32;
    if (t + 1 < nk) {
#pragma unroll
      for (int i = 0; i < 2; ++i) {
        int c = i * 256 + tid;
        int row = c >> 2, col = (c & 3) * 8;
        gl_lds16(A + (size_t)(m0 + row) * K + k0 + 32 + col,
                 (char*)As + (cur ^ 1) * 8192 + (i * 256 + w * 64) * 16);
        gl_lds16(W + (size_t)(n0 + row) * K + k0 + 32 + col,
                 (char*)Bs + (cur ^ 1) * 8192 + (i * 256 + w * 64) * 16);
      }
    }
    const unsigned short* Asb = As + cur * 4096;
    const unsigned short* Bsb = Bs + cur * 4096;
    bf16x8 af[4], bfr[4];
#pragma unroll
    for (int i = 0; i < 4; ++i)
      af[i] = *(const bf16x8*)(Asb + (wr * 64 + i * 16 + l15) * 32 + l4 * 8);
#pragma unroll
    for (int j = 0; j < 4; ++j)
      bfr[j] = *(const bf16x8*)(Bsb + (wc * 64 + j * 16 + l15) * 32 + l4 * 8);
    __builtin_amdgcn_s_setprio(1);
#pragma unroll
    for (int i = 0; i < 4; ++i)
#pragma unroll
      for (int j = 0; j < 4; ++j) acc[i][j] = mfma16(af[i], bfr[j], acc[i][j]);
    __builtin_amdgcn_s_setprio(0);
    __syncthreads();
    cur ^= 1;
  }
}

// ---------------- output projection (flat grid 256, XCD swizzle) ----------------
__global__ __launch_bounds__(256)
void out_gemm_kernel(const unsigned short* __restrict__ att, const unsigned short* __restrict__ wo,
                     const float* __restrict__ bo, float* __restrict__ out) {
  __shared__ unsigned short As[2 * 128 * 32];
  __shared__ unsigned short Bs[2 * 128 * 32];
  const int id = blockIdx.x;
  const int swz = (id & 7) * 32 + (id >> 3);
  const int m0 = (swz >> 3) * 128, n0 = (swz & 7) * 128;
  f32x4 acc[4][4];
  gemm128_bf_core(att, wo, m0, n0, HID, As, Bs, acc);

  const int tid = threadIdx.x;
  const int w = tid >> 6, lane = tid & 63;
  const int l15 = lane & 15, l4 = lane >> 4;
  const int wr = w >> 1, wc = w & 1;
#pragma unroll
  for (int i = 0; i < 4; ++i)
#pragma unroll
    for (int j = 0; j < 4; ++j)
#pragma unroll
      for (int r = 0; r < 4; ++r) {
        int grow = m0 + wr * 64 + i * 16 + l4 * 4 + r;
        int gcol = n0 + wc * 64 + j * 16 + l15;
        out[(size_t)grow * HID + gcol] = acc[i][j][r] + bo[gcol];
      }
}

// ---------------- flash attention (512 thr, paired subtiles, swapped softmax) ----------------
// flat grid 512; g = (id&7)*64 + id>>3: bh = g>>4 (same-bh blocks on one XCD), x = g&15.
__global__ __launch_bounds__(512)
void attn_kernel(const unsigned short* __restrict__ Qp, const unsigned short* __restrict__ Kp,
                 const unsigned short* __restrict__ Vtp, unsigned short* __restrict__ att,
                 const int* __restrict__ lens) {
  __shared__ unsigned short Ks[2][64 * 64];   // [buf][k][d], XOR-swizzled 16B chunks
  __shared__ unsigned short Vs[2][64 * 64];   // [buf][d][k], XOR-swizzled 16B chunks
  __shared__ unsigned short Ps[8][16 * 72];   // wave-private P [q][k], padded stride 72

  const int id = blockIdx.x;
  const int g = (id & 7) * 64 + (id >> 3);
  const int bh = g >> 4;
  const int x = g & 15;
  const int b = bh >> 4, h = bh & 15;
  const int tid = threadIdx.x, w = tid >> 6, lane = tid & 63;
  const int l15 = lane & 15, l4 = lane >> 4;
  const int len = lens[b];
  const int sub = (w < 4) ? x : (31 - x);
  const int qw0 = sub * 64 + (w & 3) * 16;

  const unsigned short* Qg = Qp + (size_t)bh * L_SEQ * HD;
  const unsigned short* Kg = Kp + (size_t)bh * L_SEQ * HD;
  const unsigned short* Vg = Vtp + (size_t)bh * HD * L_SEQ;

  const int rr = tid >> 3, cb = tid & 7;
  const int swz = (cb ^ (rr & 7)) * 8;
  const unsigned short* KgRow = Kg + (size_t)rr * HD + swz;       // + k0*HD
  const unsigned short* VgRow = Vg + (size_t)rr * L_SEQ + swz;    // + k0

  bf16x8 qf[2];
#pragma unroll
  for (int kk = 0; kk < 2; ++kk)
    qf[kk] = *(const bf16x8*)(Qg + (size_t)(qw0 + l15) * HD + kk * 32 + l4 * 8);

  f32x4 acc[4];
#pragma unroll
  for (int n = 0; n < 4; ++n) acc[n] = (f32x4){0.f, 0.f, 0.f, 0.f};
  float mq = -1e30f, lq = 0.f;

  int koff[4][2];
#pragma unroll
  for (int n = 0; n < 4; ++n)
#pragma unroll
    for (int kk = 0; kk < 2; ++kk) {
      int row = n * 16 + l15;
      koff[n][kk] = row * 128 + (((l4 + kk * 4) ^ (row & 7)) * 16);
    }

  const int len_r = ((len + 63) >> 6) << 6;
  const int hi_end = 64 * (32 - x);
  const int kv_end = (hi_end < len_r) ? hi_end : len_r;
  const int nt = kv_end >> 6;

  gl_lds16(KgRow, (char*)&Ks[0][0] + w * 1024);
  gl_lds16(VgRow, (char*)&Vs[0][0] + w * 1024);
  __syncthreads();

  int cur = 0;
  for (int t = 0; t < nt; ++t) {
    const int k0 = t * 64;
    if (t + 1 < nt) {
      const int k1 = k0 + 64;
      gl_lds16(KgRow + (size_t)k1 * HD, (char*)&Ks[cur ^ 1][0] + w * 1024);
      gl_lds16(VgRow + k1, (char*)&Vs[cur ^ 1][0] + w * 1024);
    }
    if (k0 <= qw0 + 15) {
      const char* Kb = (const char*)&Ks[cur][0];
      const char* Vb = (const char*)&Vs[cur][0];
      f32x4 s[4];
#pragma unroll
      for (int n = 0; n < 4; ++n) s[n] = (f32x4){0.f, 0.f, 0.f, 0.f};
      __builtin_amdgcn_s_setprio(1);
#pragma unroll
      for (int kk = 0; kk < 2; ++kk) {
#pragma unroll
        for (int n = 0; n < 4; ++n)
          s[n] = mfma16(*(const bf16x8*)(Kb + koff[n][kk]), qf[kk], s[n]);
      }
      __builtin_amdgcn_s_setprio(0);
      if (!(k0 + 63 <= qw0 && k0 + 64 <= len)) {
        const int qa = qw0 + l15;
#pragma unroll
        for (int n = 0; n < 4; ++n)
#pragma unroll
          for (int r = 0; r < 4; ++r) {
            int ka = k0 + n * 16 + l4 * 4 + r;
            if (ka > qa || ka >= len) s[n][r] = -1e30f;
          }
      }
      float v01 = fmaxf(fmaxf(s[0][0], s[0][1]), fmaxf(s[0][2], s[0][3]));
      float v23 = fmaxf(fmaxf(s[1][0], s[1][1]), fmaxf(s[1][2], s[1][3]));
      float v45 = fmaxf(fmaxf(s[2][0], s[2][1]), fmaxf(s[2][2], s[2][3]));
      float v67 = fmaxf(fmaxf(s[3][0], s[3][1]), fmaxf(s[3][2], s[3][3]));
      float v = fmaxf(fmaxf(v01, v23), fmaxf(v45, v67));
      v = fmaxf(v, __shfl_xor(v, 16));
      v = fmaxf(v, __shfl_xor(v, 32));
      if (!__all(v - mq <= 8.0f)) {  // defer-max (T13), exp2 domain
        float mnew = fmaxf(mq, v);
        float alpha = __builtin_amdgcn_exp2f(mq - mnew);
        mq = mnew;
        float ar[4];
#pragma unroll
        for (int r = 0; r < 4; ++r) ar[r] = __shfl(alpha, l4 * 4 + r, 64);
#pragma unroll
        for (int n = 0; n < 4; ++n)
#pragma unroll
          for (int r = 0; r < 4; ++r) acc[n][r] *= ar[r];
        lq *= alpha;
      }
      float rs = 0.f;
#pragma unroll
      for (int n = 0; n < 4; ++n)
#pragma unroll
        for (int r = 0; r < 4; ++r) {
          float p = __builtin_amdgcn_exp2f(s[n][r] - mq);
          s[n][r] = p;
          rs += p;
        }
      rs += __shfl_xor(rs, 16);
      rs += __shfl_xor(rs, 32);
      lq += rs;
#pragma unroll
      for (int n = 0; n < 4; ++n) {
        uint2 pw;
        pw.x = pk2bf(s[n][0], s[n][1]);
        pw.y = pk2bf(s[n][2], s[n][3]);
        *(uint2*)(&Ps[w][l15 * 72 + n * 16 + l4 * 4]) = pw;
      }
      bf16x8 pf[2];
#pragma unroll
      for (int kk = 0; kk < 2; ++kk)
        pf[kk] = *(const bf16x8*)(&Ps[w][l15 * 72 + kk * 32 + l4 * 8]);
      __builtin_amdgcn_s_setprio(1);
#pragma unroll
      for (int kk = 0; kk < 2; ++kk) {
#pragma unroll
        for (int n = 0; n < 4; ++n)
          acc[n] = mfma16(pf[kk], *(const bf16x8*)(Vb + koff[n][kk]), acc[n]);
      }
      __builtin_amdgcn_s_setprio(0);
    }
    __syncthreads();
    cur ^= 1;
  }

  float invq = 1.0f / lq;
  float invr[4];
#pragma unroll
  for (int r = 0; r < 4; ++r) invr[r] = __shfl(invq, l4 * 4 + r, 64);
#pragma unroll
  for (int r = 0; r < 4; ++r) {
    int qa = qw0 + l4 * 4 + r;
#pragma unroll
    for (int n = 0; n < 4; ++n)
      att[((size_t)(b * L_SEQ + qa)) * HID + h * HD + n * 16 + l15] = f2bf(acc[n][r] * invr[r]);
  }
}

extern "C" void kernel_launch(void* const* d_in, const int* in_sizes, int n_in,
                              void* d_out, int out_size, void* d_ws, size_t ws_size,
                              hipStream_t stream) {
  const float* query = (const float*)d_in[0];
  const float* key = (const float*)d_in[1];
  const float* value = (const float*)d_in[2];
  const unsigned int* key_mask = (const unsigned int*)d_in[3];
  // d_in[4] = attn_mask (static causal triu) -- computed in-kernel, unused
  const float* Wq = (const float*)d_in[5];
  const float* bq = (const float*)d_in[6];
  const float* Wk = (const float*)d_in[7];
  const float* bk = (const float*)d_in[8];
  const float* Wv = (const float*)d_in[9];
  const float* bv = (const float*)d_in[10];
  const float* Wo = (const float*)d_in[11];
  const float* bo = (const float*)d_in[12];

  char* ws = (char*)d_ws;
  const size_t SZ_X = (size_t)4096 * 1024 * 2;  // 8 MiB
  const size_t SZ_W = (size_t)1024 * 1024 * 2;  // 2 MiB
  unsigned short* wqb = (unsigned short*)(ws + 3 * SZ_X);
  unsigned short* wkb = (unsigned short*)(ws + 3 * SZ_X + SZ_W);
  unsigned short* wvb = (unsigned short*)(ws + 3 * SZ_X + 2 * SZ_W);
  unsigned short* wob = (unsigned short*)(ws + 3 * SZ_X + 3 * SZ_W);
  unsigned short* Qp = (unsigned short*)(ws + 3 * SZ_X + 4 * SZ_W);
  unsigned short* Kp = (unsigned short*)(ws + 4 * SZ_X + 4 * SZ_W);
  unsigned short* Vtp = (unsigned short*)(ws + 5 * SZ_X + 4 * SZ_W);
  unsigned short* att = (unsigned short*)(ws + 6 * SZ_X + 4 * SZ_W);
  int* lens = (int*)(ws + 7 * SZ_X + 4 * SZ_W);

  convert_w_kernel<<<2049, 256, 0, stream>>>(Wq, Wk, Wv, Wo, key_mask,
                                             wqb, wkb, wvb, wob, lens);
  qkv_gemm_kernel<<<768, 256, 0, stream>>>(query, key, value, wqb, wkb, wvb,
                                           bq, bk, bv, Qp, Kp, Vtp);
  attn_kernel<<<512, 512, 0, stream>>>(Qp, Kp, Vtp, att, lens);
  out_gemm_kernel<<<256, 256, 0, stream>>>(att, wob, bo, (float*)d_out);
}